// Round 1
// baseline (74.557 us; speedup 1.0000x reference)
//
#include <hip/hip_runtime.h>
#include <math.h>

constexpr int Bn = 32, Pn = 16, Ln = 512, Dn = 256, VOC = 50000;

// --- Kernel A: eV[v] = emb[v,:]·V / 10 ; eW[v] = emb[v,:]·W / 10 ---
__global__ __launch_bounds__(256) void k_embdot(const float* __restrict__ emb,
                                               const float* __restrict__ V,
                                               const float* __restrict__ W,
                                               float* __restrict__ eV,
                                               float* __restrict__ eW)
{
    int row  = blockIdx.x * 4 + (threadIdx.x >> 6);   // one wave64 per vocab row
    if (row >= VOC) return;
    int lane = threadIdx.x & 63;
    float4 r  = ((const float4*)(emb + (size_t)row * Dn))[lane];
    float4 v  = ((const float4*)V)[lane];
    float4 w  = ((const float4*)W)[lane];
    float dv = r.x*v.x + r.y*v.y + r.z*v.z + r.w*v.w;
    float dw = r.x*w.x + r.y*w.y + r.z*w.z + r.w*w.w;
#pragma unroll
    for (int o = 32; o; o >>= 1) { dv += __shfl_xor(dv, o); dw += __shfl_xor(dw, o); }
    if (lane == 0) { eV[row] = dv / 10.0f; eW[row] = dw / 10.0f; }
}

// --- Kernel B: per-(b,p) softmax attention, page score, webpage_vec ---
__global__ __launch_bounds__(256) void k_page(const int* __restrict__ seq_ids,
                                              const int* __restrict__ num_pages,
                                              const int* __restrict__ seq_lengths,
                                              const float* __restrict__ emb,
                                              const float* __restrict__ eV,
                                              const float* __restrict__ eW,
                                              float* __restrict__ attn_out,
                                              float* __restrict__ pscore_out,
                                              float* __restrict__ web_out)
{
    int bp = blockIdx.x;                 // 0..511
    int b  = bp >> 4, p = bp & 15;
    int tid = threadIdx.x, lane = tid & 63, wv = tid >> 6;

    __shared__ int   ids[Ln];
    __shared__ float sc[Ln];
    __shared__ float redm[4], reds[4], redp[4];

    const int* sid = seq_ids + (size_t)bp * Ln;
    int  slen = seq_lengths[bp];
    bool vp   = (p < num_pages[b]);
    int  Lv   = vp ? slen : Ln;          // nonzero-attn prefix length

    // scores via eV gather (4B/token instead of 1KB/token)
    for (int l = tid; l < Ln; l += 256) {
        int id = sid[l];
        ids[l] = id;
        sc[l]  = (vp && l >= slen) ? -999.0f : eV[id];
    }
    __syncthreads();

    // block max
    float mx = -1e30f;
    for (int l = tid; l < Ln; l += 256) mx = fmaxf(mx, sc[l]);
#pragma unroll
    for (int o = 32; o; o >>= 1) mx = fmaxf(mx, __shfl_xor(mx, o));
    if (lane == 0) redm[wv] = mx;
    __syncthreads();
    mx = fmaxf(fmaxf(redm[0], redm[1]), fmaxf(redm[2], redm[3]));

    // exp, softmax denom, and page-score numerator (linear through eW)
    float sum = 0.f, ps = 0.f;
    for (int l = tid; l < Ln; l += 256) {
        float e = expf(sc[l] - mx);      // masked: expf(~-999) == exactly 0.0f
        sc[l] = e;
        sum += e;
        ps  += e * eW[ids[l]];
    }
#pragma unroll
    for (int o = 32; o; o >>= 1) { sum += __shfl_xor(sum, o); ps += __shfl_xor(ps, o); }
    if (lane == 0) { reds[wv] = sum; redp[wv] = ps; }
    __syncthreads();
    sum = reds[0] + reds[1] + reds[2] + reds[3];
    ps  = redp[0] + redp[1] + redp[2] + redp[3];
    float inv = 1.0f / sum;

    // normalized attention -> LDS + output
    for (int l = tid; l < Ln; l += 256) {
        float a = sc[l] * inv;
        sc[l] = a;
        attn_out[(size_t)bp * Ln + l] = a;
    }
    if (tid == 0) pscore_out[bp] = vp ? ps * inv : -9999.0f;
    __syncthreads();

    // webpage_vec[d] = sum_l attn[l] * emb[id_l, d] over nonzero prefix
    float acc = 0.f;
    const float* ecol = emb + tid;       // thread owns column d = tid
#pragma unroll 4
    for (int l = 0; l < Lv; ++l) {
        acc += sc[l] * ecol[(size_t)ids[l] * Dn];
    }
    web_out[(size_t)bp * Dn + tid] = acc;
}

// --- Kernel C: sparsemax over pages, final vec, decoder, sigmoid ---
__global__ __launch_bounds__(256) void k_final(const float* __restrict__ dec_w,
                                               const float* __restrict__ pscore,
                                               const float* __restrict__ web,
                                               float* __restrict__ probs,
                                               float* __restrict__ senti,
                                               float* __restrict__ pattn,
                                               float* __restrict__ fvec)
{
    int b = blockIdx.x, tid = threadIdx.x, lane = tid & 63, wv = tid >> 6;
    __shared__ float pa[Pn];
    __shared__ float red[4];

    if (tid == 0) {
        float z[Pn], zs[Pn], csum[Pn];
        for (int i = 0; i < Pn; ++i) { z[i] = pscore[b * Pn + i]; zs[i] = z[i]; }
        // insertion sort descending (P=16)
        for (int i = 1; i < Pn; ++i) {
            float key = zs[i]; int j = i - 1;
            while (j >= 0 && zs[j] < key) { zs[j + 1] = zs[j]; --j; }
            zs[j + 1] = key;
        }
        int kmax = 0; float cs = 0.f;
        for (int k = 0; k < Pn; ++k) {
            cs += zs[k];
            csum[k] = cs;
            if (1.0f + (float)(k + 1) * zs[k] > cs) kmax = k + 1; // support count (prefix)
        }
        float tau = (csum[kmax - 1] - 1.0f) / (float)kmax;
        for (int i = 0; i < Pn; ++i) pa[i] = fmaxf(z[i] - tau, 0.0f);
    }
    __syncthreads();

    float fv = 0.f;
#pragma unroll
    for (int p = 0; p < Pn; ++p) fv += pa[p] * web[((size_t)b * Pn + p) * Dn + tid];
    fvec[(size_t)b * Dn + tid] = fv;
    if (tid < Pn) pattn[b * Pn + tid] = pa[tid];

    float t = fv * dec_w[tid];
#pragma unroll
    for (int o = 32; o; o >>= 1) t += __shfl_xor(t, o);
    if (lane == 0) red[wv] = t;
    __syncthreads();
    if (tid == 0) {
        float s = red[0] + red[1] + red[2] + red[3];
        senti[b] = s;
        probs[b] = 1.0f / (1.0f + expf(-s));
    }
}

extern "C" void kernel_launch(void* const* d_in, const int* in_sizes, int n_in,
                              void* d_out, int out_size, void* d_ws, size_t ws_size,
                              hipStream_t stream) {
    const int*   seq_ids     = (const int*)d_in[0];
    const int*   num_pages   = (const int*)d_in[1];
    const int*   seq_lengths = (const int*)d_in[2];
    const float* emb         = (const float*)d_in[3];
    const float* V           = (const float*)d_in[4];
    const float* W           = (const float*)d_in[5];
    const float* dec_w       = (const float*)d_in[6];

    float* out    = (float*)d_out;
    float* probs  = out;                                   // [B,1]     32
    float* senti  = probs + Bn;                            // [B,1]     32
    float* attn   = senti + Bn;                            // [B,P,1,L] 262144
    float* pattn  = attn  + (size_t)Bn * Pn * Ln;          // [B,1,P]   512
    float* fvec   = pattn + Bn * Pn;                       // [B,D]     8192
    float* pscore = fvec  + (size_t)Bn * Dn;               // [B,P]     512
    float* web    = pscore + Bn * Pn;                      // [B,P,D]   131072

    float* eV = (float*)d_ws;          // 50000 f32
    float* eW = eV + VOC;              // 50000 f32  (400 KB total)

    k_embdot<<<(VOC + 3) / 4, 256, 0, stream>>>(emb, V, W, eV, eW);
    k_page<<<Bn * Pn, 256, 0, stream>>>(seq_ids, num_pages, seq_lengths,
                                        emb, eV, eW, attn, pscore, web);
    k_final<<<Bn, 256, 0, stream>>>(dec_w, pscore, web, probs, senti, pattn, fvec);
}

// Round 2
// 49.734 us; speedup vs baseline: 1.4991x; 1.4991x over previous
//
#include <hip/hip_runtime.h>
#include <math.h>

constexpr int Bn = 32, Pn = 16, Ln = 512, Dn = 256, VOC = 50000;

// --- Kernel A: eV[v] = emb[v,:]·V / 10 ; eW[v] = emb[v,:]·W / 10 ---
__global__ __launch_bounds__(256) void k_embdot(const float* __restrict__ emb,
                                               const float* __restrict__ V,
                                               const float* __restrict__ W,
                                               float* __restrict__ eV,
                                               float* __restrict__ eW)
{
    int row  = blockIdx.x * 4 + (threadIdx.x >> 6);   // one wave64 per vocab row
    if (row >= VOC) return;
    int lane = threadIdx.x & 63;
    float4 r  = ((const float4*)(emb + (size_t)row * Dn))[lane];
    float4 v  = ((const float4*)V)[lane];
    float4 w  = ((const float4*)W)[lane];
    float dv = r.x*v.x + r.y*v.y + r.z*v.z + r.w*v.w;
    float dw = r.x*w.x + r.y*w.y + r.z*w.z + r.w*w.w;
#pragma unroll
    for (int o = 32; o; o >>= 1) { dv += __shfl_xor(dv, o); dw += __shfl_xor(dw, o); }
    if (lane == 0) { eV[row] = dv / 10.0f; eW[row] = dw / 10.0f; }
}

// --- Kernel B: per-(b,p) softmax attention, page score, webpage_vec ---
// 1024 threads = 16 waves. Scoring uses lanes 0..511; gather splits 512 rows
// across 16 waves (32 each), float4 per lane over D=256.
__global__ __launch_bounds__(1024) void k_page(const int* __restrict__ seq_ids,
                                               const int* __restrict__ num_pages,
                                               const int* __restrict__ seq_lengths,
                                               const float* __restrict__ emb,
                                               const float* __restrict__ eV,
                                               const float* __restrict__ eW,
                                               float* __restrict__ attn_out,
                                               float* __restrict__ pscore_out,
                                               float* __restrict__ web_out)
{
    int bp = blockIdx.x;                 // 0..511
    int b  = bp >> 4, p = bp & 15;
    int tid = threadIdx.x, lane = tid & 63, wv = tid >> 6;   // wv 0..15

    __shared__ int   ids[Ln];
    __shared__ float sc[Ln];
    __shared__ float redm[16], reds[16], redp[16];
    __shared__ float part[16][Dn];       // 16 KB partial webpage_vec

    const int* sid = seq_ids + (size_t)bp * Ln;
    int  slen = seq_lengths[bp];
    bool vp   = (p < num_pages[b]);
    int  Lv   = vp ? slen : Ln;          // nonzero-attn prefix length

    // scores via eV gather (4B/token instead of 1KB/token)
    if (tid < Ln) {
        int id = sid[tid];
        ids[tid] = id;
        sc[tid]  = (vp && tid >= slen) ? -999.0f : eV[id];
    }
    __syncthreads();

    // block max over 512 scores
    float mx = (tid < Ln) ? sc[tid] : -1e30f;
#pragma unroll
    for (int o = 32; o; o >>= 1) mx = fmaxf(mx, __shfl_xor(mx, o));
    if (lane == 0) redm[wv] = mx;
    __syncthreads();
    mx = redm[0];
#pragma unroll
    for (int w = 1; w < 16; ++w) mx = fmaxf(mx, redm[w]);

    // exp, softmax denom, and page-score numerator (linear through eW)
    float e = 0.f, pw = 0.f;
    if (tid < Ln) {
        e = expf(sc[tid] - mx);          // masked: expf(~-999) == exactly 0.0f
        sc[tid] = e;
        pw = e * eW[ids[tid]];
    }
    float sum = e, ps = pw;
#pragma unroll
    for (int o = 32; o; o >>= 1) { sum += __shfl_xor(sum, o); ps += __shfl_xor(ps, o); }
    if (lane == 0) { reds[wv] = sum; redp[wv] = ps; }
    __syncthreads();
    sum = 0.f; ps = 0.f;
#pragma unroll
    for (int w = 0; w < 16; ++w) { sum += reds[w]; ps += redp[w]; }
    float inv = 1.0f / sum;

    // normalized attention -> LDS + output
    if (tid < Ln) {
        float a = sc[tid] * inv;
        sc[tid] = a;
        attn_out[(size_t)bp * Ln + tid] = a;
    }
    if (tid == 0) pscore_out[bp] = vp ? ps * inv : -9999.0f;
    __syncthreads();

    // webpage_vec: wave wv handles rows [wv*32, wv*32+32) ∩ [0,Lv)
    float4 acc = make_float4(0.f, 0.f, 0.f, 0.f);
    int r0 = wv * 32;
    int r1 = min(r0 + 32, Lv);
#pragma unroll 4
    for (int l = r0; l < r1; ++l) {
        float4 v = ((const float4*)(emb + (size_t)ids[l] * Dn))[lane];
        float  w = sc[l];
        acc.x += w * v.x; acc.y += w * v.y; acc.z += w * v.z; acc.w += w * v.w;
    }
    ((float4*)part[wv])[lane] = acc;
    __syncthreads();

    if (tid < Dn) {
        float s = 0.f;
#pragma unroll
        for (int w = 0; w < 16; ++w) s += part[w][tid];
        web_out[(size_t)bp * Dn + tid] = s;
    }
}

// --- Kernel C: sparsemax over pages, final vec, decoder, sigmoid ---
__global__ __launch_bounds__(256) void k_final(const float* __restrict__ dec_w,
                                               const float* __restrict__ pscore,
                                               const float* __restrict__ web,
                                               float* __restrict__ probs,
                                               float* __restrict__ senti,
                                               float* __restrict__ pattn,
                                               float* __restrict__ fvec)
{
    int b = blockIdx.x, tid = threadIdx.x, lane = tid & 63, wv = tid >> 6;
    __shared__ float pa[Pn];
    __shared__ float red[4];

    if (tid == 0) {
        float z[Pn], zs[Pn], csum[Pn];
        for (int i = 0; i < Pn; ++i) { z[i] = pscore[b * Pn + i]; zs[i] = z[i]; }
        // insertion sort descending (P=16)
        for (int i = 1; i < Pn; ++i) {
            float key = zs[i]; int j = i - 1;
            while (j >= 0 && zs[j] < key) { zs[j + 1] = zs[j]; --j; }
            zs[j + 1] = key;
        }
        int kmax = 0; float cs = 0.f;
        for (int k = 0; k < Pn; ++k) {
            cs += zs[k];
            csum[k] = cs;
            if (1.0f + (float)(k + 1) * zs[k] > cs) kmax = k + 1; // support count (prefix)
        }
        float tau = (csum[kmax - 1] - 1.0f) / (float)kmax;
        for (int i = 0; i < Pn; ++i) pa[i] = fmaxf(z[i] - tau, 0.0f);
    }
    __syncthreads();

    float fv = 0.f;
#pragma unroll
    for (int p = 0; p < Pn; ++p) fv += pa[p] * web[((size_t)b * Pn + p) * Dn + tid];
    fvec[(size_t)b * Dn + tid] = fv;
    if (tid < Pn) pattn[b * Pn + tid] = pa[tid];

    float t = fv * dec_w[tid];
#pragma unroll
    for (int o = 32; o; o >>= 1) t += __shfl_xor(t, o);
    if (lane == 0) red[wv] = t;
    __syncthreads();
    if (tid == 0) {
        float s = red[0] + red[1] + red[2] + red[3];
        senti[b] = s;
        probs[b] = 1.0f / (1.0f + expf(-s));
    }
}

extern "C" void kernel_launch(void* const* d_in, const int* in_sizes, int n_in,
                              void* d_out, int out_size, void* d_ws, size_t ws_size,
                              hipStream_t stream) {
    const int*   seq_ids     = (const int*)d_in[0];
    const int*   num_pages   = (const int*)d_in[1];
    const int*   seq_lengths = (const int*)d_in[2];
    const float* emb         = (const float*)d_in[3];
    const float* V           = (const float*)d_in[4];
    const float* W           = (const float*)d_in[5];
    const float* dec_w       = (const float*)d_in[6];

    float* out    = (float*)d_out;
    float* probs  = out;                                   // [B,1]     32
    float* senti  = probs + Bn;                            // [B,1]     32
    float* attn   = senti + Bn;                            // [B,P,1,L] 262144
    float* pattn  = attn  + (size_t)Bn * Pn * Ln;          // [B,1,P]   512
    float* fvec   = pattn + Bn * Pn;                       // [B,D]     8192
    float* pscore = fvec  + (size_t)Bn * Dn;               // [B,P]     512
    float* web    = pscore + Bn * Pn;                      // [B,P,D]   131072

    float* eV = (float*)d_ws;          // 50000 f32
    float* eW = eV + VOC;              // 50000 f32  (400 KB total)

    k_embdot<<<(VOC + 3) / 4, 256, 0, stream>>>(emb, V, W, eV, eW);
    k_page<<<Bn * Pn, 1024, 0, stream>>>(seq_ids, num_pages, seq_lengths,
                                         emb, eV, eW, attn, pscore, web);
    k_final<<<Bn, 256, 0, stream>>>(dec_w, pscore, web, probs, senti, pattn, fvec);
}